// Round 1
// baseline (748.495 us; speedup 1.0000x reference)
//
#include <hip/hip_runtime.h>
#include <hip/hip_bf16.h>

#define IN_F   4096
#define OUT_F  4096
#define NTOK   8192
#define LRANK  128

typedef unsigned short u16;
typedef __attribute__((ext_vector_type(8))) __bf16 bf16x8;
typedef __attribute__((ext_vector_type(4))) float f32x4;

__device__ __forceinline__ u16 f2bf(float f) {
  union { float f; unsigned u; } a; a.f = f;
  return (u16)((a.u + 0x7fffu + ((a.u >> 16) & 1u)) >> 16);
}

// async global->LDS, 16B per lane. LDS dest is wave-uniform base + lane*16.
__device__ __forceinline__ void async_ld16(const void* g, void* l) {
  __builtin_amdgcn_global_load_lds(
      (__attribute__((address_space(1))) void*)(unsigned long long)g,
      (__attribute__((address_space(3))) void*)(unsigned int)(unsigned long long)l,
      16, 0, 0);
}

// Stage a 128x32 bf16 tile (rows [row0,row0+128), cols [col0,col0+32) of a
// row-major [*, stride] matrix) into LDS laid out [128][32].
__device__ __forceinline__ void stage_tile_128x32(const u16* __restrict__ g, int stride,
                                                  int row0, int col0,
                                                  u16* lbase, int wave, int lane) {
#pragma unroll
  for (int p = 0; p < 2; ++p) {
    int li_base = wave * 64 + p * 256;          // wave-uniform
    int li = li_base + lane;                     // [0,512): 16B chunk index
    const u16* gaddr = g + (size_t)(row0 + (li >> 2)) * stride + col0 + ((li & 3) << 3);
    async_ld16(gaddr, lbase + li_base * 8);      // HW adds lane*16B
  }
}

// ---------------- prep kernels ----------------

__global__ void cvt_bf16_kernel(const float* __restrict__ src, u16* __restrict__ dst, int n4) {
  int i = blockIdx.x * blockDim.x + threadIdx.x;
  if (i >= n4) return;
  float4 v = ((const float4*)src)[i];
  ushort4 o;
  o.x = f2bf(v.x); o.y = f2bf(v.y); o.z = f2bf(v.z); o.w = f2bf(v.w);
  ((ushort4*)dst)[i] = o;
}

// W[o][i] = f2bf(gb[o/8][i/8] + cb[(o>>6)*64 + (i>>6)][zm] * gs[o/8][i/8])
// zm flat: ((o>>6)*64 + (i>>6))*4096 + (o&63)*64 + (i&63)
__global__ void dequant_kernel(const int* __restrict__ zm, const float* __restrict__ cb,
                               const float* __restrict__ gs, const float* __restrict__ gb,
                               u16* __restrict__ W) {
  int idx = blockIdx.x * blockDim.x + threadIdx.x;   // one thread per 4 weights
  if (idx >= OUT_F * IN_F / 4) return;
  int o = idx >> 10;            // / (IN_F/4)
  int i = (idx & 1023) << 2;
  int row = ((o >> 6) << 6) + (i >> 6);              // codebook row
  const int* zp = zm + ((size_t)row << 12) + ((o & 63) << 6) + (i & 63);
  int4 z = *(const int4*)zp;
  const float* cr = cb + ((size_t)row << 8);
  int g = (o >> 3) * (IN_F / 8) + (i >> 3);          // i..i+3 share i>>3 (i%4==0)
  float s = gs[g], b = gb[g];
  ushort4 w;
  w.x = f2bf(b + cr[z.x] * s);
  w.y = f2bf(b + cr[z.y] * s);
  w.z = f2bf(b + cr[z.z] * s);
  w.w = f2bf(b + cr[z.w] * s);
  *(ushort4*)(W + (size_t)idx * 4) = w;
}

// ---------------- hid GEMM: hid[t][r] = sum_i input[t][i]*L1[r][i] ----------------
// M=8192 (blocks of 128), N=128, K=4096. 4 waves, each 64x64 subtile.

__global__ __launch_bounds__(256) void gemm_hid(const u16* __restrict__ A,
                                                const u16* __restrict__ L1,
                                                u16* __restrict__ H) {
  __shared__ __align__(16) u16 lds[2 * 128 * 32];
  u16* ldsA = lds;
  u16* ldsB = lds + 128 * 32;

  int tid = threadIdx.x;
  int wave = tid >> 6, lane = tid & 63;
  int bm0 = blockIdx.x * 128;
  int wr = (wave >> 1) * 64, wc = (wave & 1) * 64;
  int lrow = lane & 15, lk = (lane >> 4) * 8;

  f32x4 acc[4][4];
#pragma unroll
  for (int m = 0; m < 4; ++m)
#pragma unroll
    for (int n = 0; n < 4; ++n)
#pragma unroll
      for (int v = 0; v < 4; ++v) acc[m][n][v] = 0.f;

  for (int kt = 0; kt < IN_F / 32; ++kt) {
    int k0 = kt * 32;
    stage_tile_128x32(A, IN_F, bm0, k0, ldsA, wave, lane);
    stage_tile_128x32(L1, IN_F, 0, k0, ldsB, wave, lane);
    __syncthreads();
    bf16x8 af[4], bfr[4];
#pragma unroll
    for (int m = 0; m < 4; ++m)
      af[m] = *(const bf16x8*)&ldsA[(wr + m * 16 + lrow) * 32 + lk];
#pragma unroll
    for (int n = 0; n < 4; ++n)
      bfr[n] = *(const bf16x8*)&ldsB[(wc + n * 16 + lrow) * 32 + lk];
#pragma unroll
    for (int m = 0; m < 4; ++m)
#pragma unroll
      for (int n = 0; n < 4; ++n)
        acc[m][n] = __builtin_amdgcn_mfma_f32_16x16x32_bf16(af[m], bfr[n], acc[m][n], 0, 0, 0);
    __syncthreads();
  }

  int lrow4 = (lane >> 4) * 4;
#pragma unroll
  for (int m = 0; m < 4; ++m)
#pragma unroll
    for (int n = 0; n < 4; ++n)
#pragma unroll
      for (int v = 0; v < 4; ++v) {
        int rg = bm0 + wr + m * 16 + lrow4 + v;
        int cg = wc + n * 16 + lrow;
        H[(size_t)rg * LRANK + cg] = f2bf(acc[m][n][v]);
      }
}

// ---------------- main GEMM + fused low-rank epilogue ----------------
// baseline[t][o] = sum_i A[t][i]*W[o][i];  mult = hid[t]·L2[o] + scale[o];
// add = hid[t]·L2[o+4096] + bias[o];  out = add + mult*baseline.

__global__ __launch_bounds__(256) void gemm_main(const u16* __restrict__ A,
                                                 const u16* __restrict__ W,
                                                 const u16* __restrict__ H,
                                                 const u16* __restrict__ L2,
                                                 const float* __restrict__ scale,
                                                 const float* __restrict__ bias,
                                                 float* __restrict__ out) {
  __shared__ __align__(16) u16 lds[2 * 128 * 32];
  u16* ldsA = lds;
  u16* ldsB = lds + 128 * 32;

  int tid = threadIdx.x;
  int wave = tid >> 6, lane = tid & 63;
  int bm0 = blockIdx.y * 128;   // token rows
  int bn0 = blockIdx.x * 128;   // output cols
  int wr = (wave >> 1) * 64, wc = (wave & 1) * 64;
  int lrow = lane & 15, lk = (lane >> 4) * 8;

  f32x4 acc[4][4];
#pragma unroll
  for (int m = 0; m < 4; ++m)
#pragma unroll
    for (int n = 0; n < 4; ++n)
#pragma unroll
      for (int v = 0; v < 4; ++v) acc[m][n][v] = 0.f;

  for (int kt = 0; kt < IN_F / 32; ++kt) {
    int k0 = kt * 32;
    stage_tile_128x32(A, IN_F, bm0, k0, ldsA, wave, lane);
    stage_tile_128x32(W, IN_F, bn0, k0, ldsB, wave, lane);
    __syncthreads();
    bf16x8 af[4], bfr[4];
#pragma unroll
    for (int m = 0; m < 4; ++m)
      af[m] = *(const bf16x8*)&ldsA[(wr + m * 16 + lrow) * 32 + lk];
#pragma unroll
    for (int n = 0; n < 4; ++n)
      bfr[n] = *(const bf16x8*)&ldsB[(wc + n * 16 + lrow) * 32 + lk];
#pragma unroll
    for (int m = 0; m < 4; ++m)
#pragma unroll
      for (int n = 0; n < 4; ++n)
        acc[m][n] = __builtin_amdgcn_mfma_f32_16x16x32_bf16(af[m], bfr[n], acc[m][n], 0, 0, 0);
    __syncthreads();
  }

  // per-lane scale/bias for the 4 n-fragments
  float scl[4], bs_[4];
#pragma unroll
  for (int n = 0; n < 4; ++n) {
    int cg = bn0 + wc + n * 16 + lrow;
    scl[n] = scale[cg];
    bs_[n] = bias[cg];
  }

  // ---- pass 1: multiplicative (K = 128 over hid x L2[bn0..]) ----
  f32x4 macc[4][4];
#pragma unroll
  for (int m = 0; m < 4; ++m)
#pragma unroll
    for (int n = 0; n < 4; ++n)
#pragma unroll
      for (int v = 0; v < 4; ++v) macc[m][n][v] = 0.f;

  for (int kc = 0; kc < 4; ++kc) {
    stage_tile_128x32(H, LRANK, bm0, kc * 32, ldsA, wave, lane);
    stage_tile_128x32(L2, LRANK, bn0, kc * 32, ldsB, wave, lane);
    __syncthreads();
    bf16x8 hf[4], lf[4];
#pragma unroll
    for (int m = 0; m < 4; ++m)
      hf[m] = *(const bf16x8*)&ldsA[(wr + m * 16 + lrow) * 32 + lk];
#pragma unroll
    for (int n = 0; n < 4; ++n)
      lf[n] = *(const bf16x8*)&ldsB[(wc + n * 16 + lrow) * 32 + lk];
#pragma unroll
    for (int m = 0; m < 4; ++m)
#pragma unroll
      for (int n = 0; n < 4; ++n)
        macc[m][n] = __builtin_amdgcn_mfma_f32_16x16x32_bf16(hf[m], lf[n], macc[m][n], 0, 0, 0);
    __syncthreads();
  }

  // fold: acc = baseline * (lr_mult + scale)
#pragma unroll
  for (int m = 0; m < 4; ++m)
#pragma unroll
    for (int n = 0; n < 4; ++n)
#pragma unroll
      for (int v = 0; v < 4; ++v) {
        acc[m][n][v] *= (macc[m][n][v] + scl[n]);
        macc[m][n][v] = 0.f;
      }

  // ---- pass 2: additive (K = 128 over hid x L2[4096+bn0..]) ----
  for (int kc = 0; kc < 4; ++kc) {
    stage_tile_128x32(H, LRANK, bm0, kc * 32, ldsA, wave, lane);
    stage_tile_128x32(L2, LRANK, OUT_F + bn0, kc * 32, ldsB, wave, lane);
    __syncthreads();
    bf16x8 hf[4], lf[4];
#pragma unroll
    for (int m = 0; m < 4; ++m)
      hf[m] = *(const bf16x8*)&ldsA[(wr + m * 16 + lrow) * 32 + lk];
#pragma unroll
    for (int n = 0; n < 4; ++n)
      lf[n] = *(const bf16x8*)&ldsB[(wc + n * 16 + lrow) * 32 + lk];
#pragma unroll
    for (int m = 0; m < 4; ++m)
#pragma unroll
      for (int n = 0; n < 4; ++n)
        macc[m][n] = __builtin_amdgcn_mfma_f32_16x16x32_bf16(hf[m], lf[n], macc[m][n], 0, 0, 0);
    __syncthreads();
  }

  int lrow4 = (lane >> 4) * 4;
#pragma unroll
  for (int m = 0; m < 4; ++m)
#pragma unroll
    for (int n = 0; n < 4; ++n)
#pragma unroll
      for (int v = 0; v < 4; ++v) {
        int rg = bm0 + wr + m * 16 + lrow4 + v;
        int cg = bn0 + wc + n * 16 + lrow;
        out[(size_t)rg * OUT_F + cg] = acc[m][n][v] + macc[m][n][v] + bs_[n];
      }
}

// ---------------- launch ----------------

extern "C" void kernel_launch(void* const* d_in, const int* in_sizes, int n_in,
                              void* d_out, int out_size, void* d_ws, size_t ws_size,
                              hipStream_t stream) {
  const float* input = (const float*)d_in[0];
  const int*   zm    = (const int*)d_in[1];
  const float* cb    = (const float*)d_in[2];
  const float* l1    = (const float*)d_in[3];
  const float* l2    = (const float*)d_in[4];
  const float* gs    = (const float*)d_in[5];
  const float* gb    = (const float*)d_in[6];
  const float* scale = (const float*)d_in[7];
  const float* bias  = (const float*)d_in[8];
  float* out = (float*)d_out;

  // workspace layout (bytes)
  const size_t OFF_A  = 0;                         // input bf16: 8192*4096*2 = 64 MiB
  const size_t OFF_W  = OFF_A + (size_t)NTOK * IN_F * 2;          // 32 MiB
  const size_t OFF_L1 = OFF_W + (size_t)OUT_F * IN_F * 2;         // 1 MiB
  const size_t OFF_L2 = OFF_L1 + (size_t)LRANK * IN_F * 2;        // 2 MiB
  const size_t OFF_H  = OFF_L2 + (size_t)2 * OUT_F * LRANK * 2;   // 2 MiB
  const size_t NEED   = OFF_H + (size_t)NTOK * LRANK * 2;
  if (ws_size < NEED) return;  // workspace too small: fail loudly via wrong output

  char* ws = (char*)d_ws;
  u16* A   = (u16*)(ws + OFF_A);
  u16* W   = (u16*)(ws + OFF_W);
  u16* L1b = (u16*)(ws + OFF_L1);
  u16* L2b = (u16*)(ws + OFF_L2);
  u16* H   = (u16*)(ws + OFF_H);

  cvt_bf16_kernel<<<(NTOK * IN_F / 4) / 256, 256, 0, stream>>>(input, A, NTOK * IN_F / 4);
  cvt_bf16_kernel<<<(LRANK * IN_F / 4) / 256, 256, 0, stream>>>(l1, L1b, LRANK * IN_F / 4);
  cvt_bf16_kernel<<<(2 * OUT_F * LRANK / 4) / 256, 256, 0, stream>>>(l2, L2b, 2 * OUT_F * LRANK / 4);
  dequant_kernel<<<(OUT_F * IN_F / 4) / 256, 256, 0, stream>>>(zm, cb, gs, gb, W);

  gemm_hid<<<NTOK / 128, 256, 0, stream>>>(A, L1b, H);

  dim3 grid(OUT_F / 128, NTOK / 128);
  gemm_main<<<grid, 256, 0, stream>>>(A, W, H, L2b, scale, bias, out);
}

// Round 2
// 520.578 us; speedup vs baseline: 1.4378x; 1.4378x over previous
//
#include <hip/hip_runtime.h>
#include <hip/hip_bf16.h>

#define IN_F   4096
#define OUT_F  4096
#define NTOK   8192
#define LRANK  128

typedef unsigned short u16;
typedef __attribute__((ext_vector_type(8))) __bf16 bf16x8;
typedef __attribute__((ext_vector_type(4))) float f32x4;

__device__ __forceinline__ u16 f2bf(float f) {
  union { float f; unsigned u; } a; a.f = f;
  return (u16)((a.u + 0x7fffu + ((a.u >> 16) & 1u)) >> 16);
}

// async global->LDS, 16B per lane. LDS dest is wave-uniform base + lane*16.
__device__ __forceinline__ void async_ld16(const void* g, void* l) {
  __builtin_amdgcn_global_load_lds(
      (__attribute__((address_space(1))) void*)(unsigned long long)g,
      (__attribute__((address_space(3))) void*)(unsigned int)(unsigned long long)l,
      16, 0, 0);
}

// Stage a 128x32 bf16 tile (rows [row0,row0+128), cols [col0,col0+32) of a
// row-major [*, stride] matrix) into LDS laid out [128][32].
__device__ __forceinline__ void stage_tile_128x32(const u16* __restrict__ g, int stride,
                                                  int row0, int col0,
                                                  u16* lbase, int wave, int lane) {
#pragma unroll
  for (int p = 0; p < 2; ++p) {
    int li_base = wave * 64 + p * 256;          // wave-uniform
    int li = li_base + lane;                     // [0,512): 16B chunk index
    const u16* gaddr = g + (size_t)(row0 + (li >> 2)) * stride + col0 + ((li & 3) << 3);
    async_ld16(gaddr, lbase + li_base * 8);      // HW adds lane*16B
  }
}

// ---------------- prep kernels ----------------

__global__ void cvt_bf16_kernel(const float* __restrict__ src, u16* __restrict__ dst, int n4) {
  int i = blockIdx.x * blockDim.x + threadIdx.x;
  if (i >= n4) return;
  float4 v = ((const float4*)src)[i];
  ushort4 o;
  o.x = f2bf(v.x); o.y = f2bf(v.y); o.z = f2bf(v.z); o.w = f2bf(v.w);
  ((ushort4*)dst)[i] = o;
}

// W[o][i] = f2bf(gb[o/8][i/8] + cb[(o>>6)*64 + (i>>6)][zm] * gs[o/8][i/8])
__global__ void dequant_kernel(const int* __restrict__ zm, const float* __restrict__ cb,
                               const float* __restrict__ gs, const float* __restrict__ gb,
                               u16* __restrict__ W) {
  int idx = blockIdx.x * blockDim.x + threadIdx.x;   // one thread per 4 weights
  if (idx >= OUT_F * IN_F / 4) return;
  int o = idx >> 10;            // / (IN_F/4)
  int i = (idx & 1023) << 2;
  int row = ((o >> 6) << 6) + (i >> 6);              // codebook row
  const int* zp = zm + ((size_t)row << 12) + ((o & 63) << 6) + (i & 63);
  int4 z = *(const int4*)zp;
  const float* cr = cb + ((size_t)row << 8);
  int g = (o >> 3) * (IN_F / 8) + (i >> 3);
  float s = gs[g], b = gb[g];
  ushort4 w;
  w.x = f2bf(b + cr[z.x] * s);
  w.y = f2bf(b + cr[z.y] * s);
  w.z = f2bf(b + cr[z.z] * s);
  w.w = f2bf(b + cr[z.w] * s);
  *(ushort4*)(W + (size_t)idx * 4) = w;
}

// ---------------- hid GEMM: hid[t][r] = sum_i input[t][i]*L1[r][i] ----------------

__global__ __launch_bounds__(256) void gemm_hid(const u16* __restrict__ A,
                                                const u16* __restrict__ L1,
                                                u16* __restrict__ H) {
  __shared__ __align__(16) u16 lds[2 * 128 * 32];
  u16* ldsA = lds;
  u16* ldsB = lds + 128 * 32;

  int tid = threadIdx.x;
  int wave = tid >> 6, lane = tid & 63;
  int bm0 = blockIdx.x * 128;
  int wr = (wave >> 1) * 64, wc = (wave & 1) * 64;
  int lrow = lane & 15, lk = (lane >> 4) * 8;

  f32x4 acc[4][4];
#pragma unroll
  for (int m = 0; m < 4; ++m)
#pragma unroll
    for (int n = 0; n < 4; ++n)
#pragma unroll
      for (int v = 0; v < 4; ++v) acc[m][n][v] = 0.f;

  for (int kt = 0; kt < IN_F / 32; ++kt) {
    int k0 = kt * 32;
    stage_tile_128x32(A, IN_F, bm0, k0, ldsA, wave, lane);
    stage_tile_128x32(L1, IN_F, 0, k0, ldsB, wave, lane);
    __syncthreads();
    bf16x8 af[4], bfr[4];
#pragma unroll
    for (int m = 0; m < 4; ++m)
      af[m] = *(const bf16x8*)&ldsA[(wr + m * 16 + lrow) * 32 + lk];
#pragma unroll
    for (int n = 0; n < 4; ++n)
      bfr[n] = *(const bf16x8*)&ldsB[(wc + n * 16 + lrow) * 32 + lk];
#pragma unroll
    for (int m = 0; m < 4; ++m)
#pragma unroll
      for (int n = 0; n < 4; ++n)
        acc[m][n] = __builtin_amdgcn_mfma_f32_16x16x32_bf16(af[m], bfr[n], acc[m][n], 0, 0, 0);
    __syncthreads();
  }

  int lrow4 = (lane >> 4) * 4;
#pragma unroll
  for (int m = 0; m < 4; ++m)
#pragma unroll
    for (int n = 0; n < 4; ++n)
#pragma unroll
      for (int v = 0; v < 4; ++v) {
        int rg = bm0 + wr + m * 16 + lrow4 + v;
        int cg = wc + n * 16 + lrow;
        H[(size_t)rg * LRANK + cg] = f2bf(acc[m][n][v]);
      }
}

// ---------------- main GEMM + fused low-rank epilogue ----------------
// One low-rank pass: macc[m][j] += sum over K=128 of H-frag x L2-frag for
// n-columns (2h+j). Stages full 128x32 tiles of H and L2-rows l2row0..+128.
__device__ __forceinline__ void lr_pass(const u16* __restrict__ H,
                                        const u16* __restrict__ L2,
                                        int bm0, int l2row0, int h,
                                        int wr, int wc, int wave, int lane,
                                        u16* ldsA, u16* ldsB, f32x4 macc[4][2]) {
  int lrow = lane & 15, lk = (lane >> 4) * 8;
  for (int kc = 0; kc < 4; ++kc) {
    stage_tile_128x32(H, LRANK, bm0, kc * 32, ldsA, wave, lane);
    stage_tile_128x32(L2, LRANK, l2row0, kc * 32, ldsB, wave, lane);
    __syncthreads();
    bf16x8 hf[4], lf[2];
#pragma unroll
    for (int m = 0; m < 4; ++m)
      hf[m] = *(const bf16x8*)&ldsA[(wr + m * 16 + lrow) * 32 + lk];
#pragma unroll
    for (int j = 0; j < 2; ++j)
      lf[j] = *(const bf16x8*)&ldsB[(wc + (2 * h + j) * 16 + lrow) * 32 + lk];
#pragma unroll
    for (int m = 0; m < 4; ++m)
#pragma unroll
      for (int j = 0; j < 2; ++j)
        macc[m][j] = __builtin_amdgcn_mfma_f32_16x16x32_bf16(hf[m], lf[j], macc[m][j], 0, 0, 0);
    __syncthreads();
  }
}

__global__ __launch_bounds__(256, 2) void gemm_main(const u16* __restrict__ A,
                                                    const u16* __restrict__ W,
                                                    const u16* __restrict__ H,
                                                    const u16* __restrict__ L2,
                                                    const float* __restrict__ scale,
                                                    const float* __restrict__ bias,
                                                    float* __restrict__ out) {
  __shared__ __align__(16) u16 lds[2 * 128 * 32];
  u16* ldsA = lds;
  u16* ldsB = lds + 128 * 32;

  int tid = threadIdx.x;
  int wave = tid >> 6, lane = tid & 63;
  int bm0 = blockIdx.y * 128;   // token rows
  int bn0 = blockIdx.x * 128;   // output cols
  int wr = (wave >> 1) * 64, wc = (wave & 1) * 64;
  int lrow = lane & 15, lk = (lane >> 4) * 8;

  f32x4 acc[4][4];
#pragma unroll
  for (int m = 0; m < 4; ++m)
#pragma unroll
    for (int n = 0; n < 4; ++n)
#pragma unroll
      for (int v = 0; v < 4; ++v) acc[m][n][v] = 0.f;

  for (int kt = 0; kt < IN_F / 32; ++kt) {
    int k0 = kt * 32;
    stage_tile_128x32(A, IN_F, bm0, k0, ldsA, wave, lane);
    stage_tile_128x32(W, IN_F, bn0, k0, ldsB, wave, lane);
    __syncthreads();
    bf16x8 af[4], bfr[4];
#pragma unroll
    for (int m = 0; m < 4; ++m)
      af[m] = *(const bf16x8*)&ldsA[(wr + m * 16 + lrow) * 32 + lk];
#pragma unroll
    for (int n = 0; n < 4; ++n)
      bfr[n] = *(const bf16x8*)&ldsB[(wc + n * 16 + lrow) * 32 + lk];
#pragma unroll
    for (int m = 0; m < 4; ++m)
#pragma unroll
      for (int n = 0; n < 4; ++n)
        acc[m][n] = __builtin_amdgcn_mfma_f32_16x16x32_bf16(af[m], bfr[n], acc[m][n], 0, 0, 0);
    __syncthreads();
  }

  // per-lane scale/bias for the 4 n-fragments
  float scl[4], bs_[4];
#pragma unroll
  for (int n = 0; n < 4; ++n) {
    int cg = bn0 + wc + n * 16 + lrow;
    scl[n] = scale[cg];
    bs_[n] = bias[cg];
  }

  // ---- low-rank epilogue, 4 passes of macc[4][2] to keep regs <= 256 ----
  f32x4 macc[4][2];

  // mult, n-half 0 and 1: acc *= (lr_mult + scale)
#pragma unroll
  for (int h = 0; h < 2; ++h) {
#pragma unroll
    for (int m = 0; m < 4; ++m)
#pragma unroll
      for (int j = 0; j < 2; ++j)
#pragma unroll
        for (int v = 0; v < 4; ++v) macc[m][j][v] = 0.f;
    lr_pass(H, L2, bm0, bn0, h, wr, wc, wave, lane, ldsA, ldsB, macc);
#pragma unroll
    for (int m = 0; m < 4; ++m)
#pragma unroll
      for (int j = 0; j < 2; ++j)
#pragma unroll
        for (int v = 0; v < 4; ++v)
          acc[m][2 * h + j][v] *= (macc[m][j][v] + scl[2 * h + j]);
  }

  // add, n-half 0 and 1: acc += lr_add + bias
#pragma unroll
  for (int h = 0; h < 2; ++h) {
#pragma unroll
    for (int m = 0; m < 4; ++m)
#pragma unroll
      for (int j = 0; j < 2; ++j)
#pragma unroll
        for (int v = 0; v < 4; ++v) macc[m][j][v] = 0.f;
    lr_pass(H, L2, bm0, OUT_F + bn0, h, wr, wc, wave, lane, ldsA, ldsB, macc);
#pragma unroll
    for (int m = 0; m < 4; ++m)
#pragma unroll
      for (int j = 0; j < 2; ++j)
#pragma unroll
        for (int v = 0; v < 4; ++v)
          acc[m][2 * h + j][v] += macc[m][j][v] + bs_[2 * h + j];
  }

  int lrow4 = (lane >> 4) * 4;
#pragma unroll
  for (int m = 0; m < 4; ++m)
#pragma unroll
    for (int n = 0; n < 4; ++n)
#pragma unroll
      for (int v = 0; v < 4; ++v) {
        int rg = bm0 + wr + m * 16 + lrow4 + v;
        int cg = bn0 + wc + n * 16 + lrow;
        out[(size_t)rg * OUT_F + cg] = acc[m][n][v];
      }
}

// ---------------- launch ----------------

extern "C" void kernel_launch(void* const* d_in, const int* in_sizes, int n_in,
                              void* d_out, int out_size, void* d_ws, size_t ws_size,
                              hipStream_t stream) {
  const float* input = (const float*)d_in[0];
  const int*   zm    = (const int*)d_in[1];
  const float* cb    = (const float*)d_in[2];
  const float* l1    = (const float*)d_in[3];
  const float* l2    = (const float*)d_in[4];
  const float* gs    = (const float*)d_in[5];
  const float* gb    = (const float*)d_in[6];
  const float* scale = (const float*)d_in[7];
  const float* bias  = (const float*)d_in[8];
  float* out = (float*)d_out;

  // workspace layout (bytes)
  const size_t OFF_A  = 0;                                        // 64 MiB
  const size_t OFF_W  = OFF_A + (size_t)NTOK * IN_F * 2;          // 32 MiB
  const size_t OFF_L1 = OFF_W + (size_t)OUT_F * IN_F * 2;         // 1 MiB
  const size_t OFF_L2 = OFF_L1 + (size_t)LRANK * IN_F * 2;        // 2 MiB
  const size_t OFF_H  = OFF_L2 + (size_t)2 * OUT_F * LRANK * 2;   // 2 MiB
  const size_t NEED   = OFF_H + (size_t)NTOK * LRANK * 2;
  if (ws_size < NEED) return;

  char* ws = (char*)d_ws;
  u16* A   = (u16*)(ws + OFF_A);
  u16* W   = (u16*)(ws + OFF_W);
  u16* L1b = (u16*)(ws + OFF_L1);
  u16* L2b = (u16*)(ws + OFF_L2);
  u16* H   = (u16*)(ws + OFF_H);

  cvt_bf16_kernel<<<(NTOK * IN_F / 4) / 256, 256, 0, stream>>>(input, A, NTOK * IN_F / 4);
  cvt_bf16_kernel<<<(LRANK * IN_F / 4) / 256, 256, 0, stream>>>(l1, L1b, LRANK * IN_F / 4);
  cvt_bf16_kernel<<<(2 * OUT_F * LRANK / 4) / 256, 256, 0, stream>>>(l2, L2b, 2 * OUT_F * LRANK / 4);
  dequant_kernel<<<(OUT_F * IN_F / 4) / 256, 256, 0, stream>>>(zm, cb, gs, gb, W);

  gemm_hid<<<NTOK / 128, 256, 0, stream>>>(A, L1b, H);

  dim3 grid(OUT_F / 128, NTOK / 128);
  gemm_main<<<grid, 256, 0, stream>>>(A, W, H, L2b, scale, bias, out);
}